// Round 12
// baseline (1259.172 us; speedup 1.0000x reference)
//
#include <hip/hip_runtime.h>
#include <math.h>

#define BB 1024
#define TT 512
#define FF 32
#define HH 64
#define GG 256   // 4H
#define TC 64
#define NCHUNK (TT/TC)   // 8
#define MB 16            // batch rows per group
#define NBLK2 32         // blocks per segment (32 rows per block = 2 groups)
#define HPAD 68          // h_lds row stride
#define EPSBN 1e-3f

typedef __attribute__((ext_vector_type(8))) short bf16x8;
typedef __attribute__((ext_vector_type(4))) float f32x4;
typedef __attribute__((ext_vector_type(4))) int   i32x4;
typedef unsigned short ushort_t;

// ---------------- fold1: per-layer BN vectors + attention vector ----------------
__global__ void fold1_kernel(const float* __restrict__ gamma, const float* __restrict__ beta,
                             const float* __restrict__ mean, const float* __restrict__ var,
                             const float* __restrict__ attw, const float* __restrict__ attv,
                             float* __restrict__ s_out, float* __restrict__ ab_out,
                             float* __restrict__ wv_out) {
    int d = threadIdx.x; // 64 threads
    float s = gamma[d] * rsqrtf(var[d] + EPSBN);
    float ab = beta[d] - mean[d] * s;
    float wvr = 0.f;
    for (int e = 0; e < HH; ++e) wvr += attw[d * HH + e] * attv[e];
    s_out[d] = s;
    ab_out[d] = ab;
    wv_out[d] = s * wvr;
}

// ---------------- fold2: fold previous layer's BN into next W, b ----------------
__global__ void fold2_kernel(const float* __restrict__ W, const float* __restrict__ b,
                             const float* __restrict__ s_prev, const float* __restrict__ ab_prev,
                             float* __restrict__ Wp, float* __restrict__ bp) {
    int g = threadIdx.x; // 256 threads
    float bacc = b[g];
    for (int d = 0; d < HH; ++d) {
        float w = W[d * GG + g];
        bacc += ab_prev[d] * w;
        Wp[d * GG + g] = s_prev[d] * w;
    }
    bp[g] = bacc;
}

// ---------------- init per-call state ----------------
__global__ void init_kernel(float* st_h, float* st_c, float* st_acc, float* st_m, float* st_d) {
    int i = blockIdx.x * blockDim.x + threadIdx.x;
    int n = 3 * BB * HH;
    if (i < n) { st_h[i] = 0.f; st_c[i] = 0.f; st_acc[i] = 0.f; }
    if (i < 3 * BB) { st_m[i] = -3.0e38f; st_d[i] = 0.f; }
}

// ---------------- helpers ----------------
__device__ __forceinline__ f32x4 ld4(const float* p) { return *reinterpret_cast<const f32x4*>(p); }
__device__ __forceinline__ void st4(float* p, f32x4 v) { *reinterpret_cast<f32x4*>(p) = v; }
__device__ __forceinline__ bf16x8 ldbf(const ushort_t* p) { return *reinterpret_cast<const bf16x8*>(p); }
__device__ __forceinline__ int cvtpk(float a, float b) {
    int r; asm("v_cvt_pk_bf16_f32 %0, %1, %2" : "=v"(r) : "v"(a), "v"(b)); return r;
}
// split 8 fp32 (k-order) into hi/lo bf16x8 fragments (hi RNE; lo = residual)
__device__ __forceinline__ void mkfrag(f32x4 A, f32x4 B, bf16x8& hi, bf16x8& lo) {
    i32x4 H, L;
    H[0] = cvtpk(A[0], A[1]); H[1] = cvtpk(A[2], A[3]);
    H[2] = cvtpk(B[0], B[1]); H[3] = cvtpk(B[2], B[3]);
    L[0] = cvtpk(A[0] - __int_as_float(H[0] << 16), A[1] - __int_as_float(H[0] & 0xffff0000));
    L[1] = cvtpk(A[2] - __int_as_float(H[1] << 16), A[3] - __int_as_float(H[1] & 0xffff0000));
    L[2] = cvtpk(B[0] - __int_as_float(H[2] << 16), B[1] - __int_as_float(H[2] & 0xffff0000));
    L[3] = cvtpk(B[2] - __int_as_float(H[3] << 16), B[3] - __int_as_float(H[3] & 0xffff0000));
    hi = __builtin_bit_cast(bf16x8, H); lo = __builtin_bit_cast(bf16x8, L);
}
__device__ __forceinline__ float sigm(float x) { return __fdividef(1.f, 1.f + __expf(-x)); }
#define MFMA(a, b, c) c = __builtin_amdgcn_mfma_f32_16x16x32_bf16(a, b, c, 0, 0, 0)

// ---------------- prep: fp32 weight matrix -> hi/lo bf16 A-fragments, per-lane layout ----
__global__ void prep_frags(const float* __restrict__ M, int KT, ushort_t* __restrict__ outF) {
    int idx = blockIdx.x * 256 + threadIdx.x;
    int tot = 16 * KT * 512;
    if (idx >= tot) return;
    int e = idx & 7, l = (idx >> 3) & 63, f = idx >> 9;
    int kt = f % KT, gw = f / KT;
    int g = gw & 3, w = gw >> 2;
    int r = l & 15, q = l >> 4;
    int k = 32 * kt + 8 * q + e;
    int col = 64 * g + 16 * w + r;
    float v = M[(size_t)k * GG + col];
    int hb = cvtpk(v, v) & 0xffff;
    float hf = __int_as_float(hb << 16);
    float lo = v - hf;
    int lb = cvtpk(lo, lo) & 0xffff;
    outF[(size_t)(f * 2 + 0) * 512 + l * 8 + e] = (ushort_t)hb;
    outF[(size_t)(f * 2 + 1) * 512 + l * 8 + e] = (ushort_t)lb;
}

// ---------------- prep: fp32 array -> hi/lo bf16 planes (elementwise, vectorized) ----
__global__ void prep_planes(const float* __restrict__ in, ushort_t* __restrict__ hi,
                            ushort_t* __restrict__ lo, int n4) {
    int i = blockIdx.x * 256 + threadIdx.x;
    if (i >= n4) return;
    f32x4 v = reinterpret_cast<const f32x4*>(in)[i];
    int p0 = cvtpk(v[0], v[1]), p1 = cvtpk(v[2], v[3]);
    float a0 = v[0] - __int_as_float(p0 << 16);
    float a1 = v[1] - __int_as_float(p0 & 0xffff0000);
    float a2 = v[2] - __int_as_float(p1 << 16);
    float a3 = v[3] - __int_as_float(p1 & 0xffff0000);
    int q0 = cvtpk(a0, a1), q1 = cvtpk(a2, a3);
    reinterpret_cast<int2*>(hi)[i] = make_int2(p0, p1);
    reinterpret_cast<int2*>(lo)[i] = make_int2(q0, q1);
}

// ---------------- MFMA recurrent kernel: 2 independent 16-row groups per block ----------
// Block = 512 threads = 8 waves = 2 groups (waves 0-3: rows b0..+15, waves 4-7: +16..+31).
// Each SIMD hosts 2 waves with independent dependency chains -> latency hiding.
// Per group: wave w owns gate-cols {64g+16w+..}; lane (r,q) holds all 4 gates of
// (row r, units 16w+4q..+4) -> in-lane c/h update. U 3-term, W 3-term hi/lo bf16.
struct RecFArgs {
    const ushort_t* xhi[3]; const ushort_t* xlo[3]; long sB[3]; long sT[3]; int K[3];
    const ushort_t* UF[3]; const ushort_t* WF[3]; const float* bias[3];
    ushort_t* Hhi[3]; ushort_t* Hlo[3];   // nullptr -> skip
    float* st_h[3]; float* st_c[3]; float* st_acc[3];
    float* st_m[3]; float* st_d[3];
    const float* wv[3]; const float* abv[3]; const float* sbn[3];
    float* a_out[3];
    int last[3]; int first[3];
};

template<int KT>   // x K-tiles: 1 (K=32, layer1) or 2 (K=64)
__device__ __forceinline__ void rec_body(const RecFArgs& A, const int seg, const int b0,
                                         const int tid, float (*hl)[MB][HPAD]) {
    const int w = tid >> 6;       // group-local wave 0..3
    const int l = tid & 63;
    const int r = l & 15;
    const int q = l >> 4;
    const int cw = w << 4;
    const int grow = b0 + r;

    const bf16x8* UF = reinterpret_cast<const bf16x8*>(A.UF[seg]);
    const bf16x8* WF = reinterpret_cast<const bf16x8*>(A.WF[seg]);
#define LDU(g,kt,p_) UF[(((((w<<2)+(g))*2+(kt))*2)+(p_))*64 + l]
#define LDW(g,kt,p_) WF[(((((w<<2)+(g))*KT+(kt))*2)+(p_))*64 + l]
    bf16x8 uh00=LDU(0,0,0), uh01=LDU(0,1,0), uh10=LDU(1,0,0), uh11=LDU(1,1,0),
           uh20=LDU(2,0,0), uh21=LDU(2,1,0), uh30=LDU(3,0,0), uh31=LDU(3,1,0);
    bf16x8 ul00=LDU(0,0,1), ul01=LDU(0,1,1), ul10=LDU(1,0,1), ul11=LDU(1,1,1),
           ul20=LDU(2,0,1), ul21=LDU(2,1,1), ul30=LDU(3,0,1), ul31=LDU(3,1,1);
    bf16x8 wh00=LDW(0,0,0), wh10=LDW(1,0,0), wh20=LDW(2,0,0), wh30=LDW(3,0,0);
    bf16x8 wl00=LDW(0,0,1), wl10=LDW(1,0,1), wl20=LDW(2,0,1), wl30=LDW(3,0,1);
    bf16x8 wh01{}, wh11{}, wh21{}, wh31{}, wl01{}, wl11{}, wl21{}, wl31{};
    if constexpr (KT == 2) {
        wh01=LDW(0,1,0); wh11=LDW(1,1,0); wh21=LDW(2,1,0); wh31=LDW(3,1,0);
        wl01=LDW(0,1,1); wl11=LDW(1,1,1); wl21=LDW(2,1,1); wl31=LDW(3,1,1);
    }

    f32x4 bias40 = ld4(A.bias[seg] +   0 + cw + 4 * q);
    f32x4 bias41 = ld4(A.bias[seg] +  64 + cw + 4 * q);
    f32x4 bias42 = ld4(A.bias[seg] + 128 + cw + 4 * q);
    f32x4 bias43 = ld4(A.bias[seg] + 192 + cw + 4 * q);
    f32x4 wva = ld4(A.wv[seg] + 8 * q);
    f32x4 wvb = ld4(A.wv[seg] + 8 * q + 4);
    f32x4 wvc = ld4(A.wv[seg] + 32 + 8 * q);
    f32x4 wvd = ld4(A.wv[seg] + 32 + 8 * q + 4);

    f32x4 c4   = ld4(A.st_c[seg]   + (size_t)grow * HH + cw + 4 * q);
    f32x4 h4   = ld4(A.st_h[seg]   + (size_t)grow * HH + cw + 4 * q);
    f32x4 acc4 = ld4(A.st_acc[seg] + (size_t)grow * HH + cw + 4 * q);
    float m_b = A.st_m[seg][grow];
    float d_b = A.st_d[seg][grow];

    st4(&hl[0][r][cw + 4 * q], h4);

    const ushort_t* xhib = A.xhi[seg] + (size_t)grow * A.sB[seg];
    const ushort_t* xlob = A.xlo[seg] + (size_t)grow * A.sB[seg];
    const long sT = A.sT[seg];

    // x fragments for t=0 (pre-built hi/lo planes)
    bf16x8 xh0 = ldbf(xhib + 8 * q), xl0 = ldbf(xlob + 8 * q);
    bf16x8 xh1{}, xl1{};
    if constexpr (KT == 2) { xh1 = ldbf(xhib + 32 + 8 * q); xl1 = ldbf(xlob + 32 + 8 * q); }
    __syncthreads();

    const bool first = A.first[seg] != 0;
    ushort_t* Hhi = A.Hhi[seg];
    ushort_t* Hlo = A.Hlo[seg];

#pragma unroll 2
    for (int t = 0; t < TC; ++t) {
        const int pr = t & 1;
        // LDS reads of h_{t-1} (issued first; seed MFMAs below cover the latency)
        f32x4 f0 = ld4(&hl[pr][r][8 * q]);
        f32x4 f1 = ld4(&hl[pr][r][8 * q + 4]);
        f32x4 f2 = ld4(&hl[pr][r][32 + 8 * q]);
        f32x4 f3 = ld4(&hl[pr][r][32 + 8 * q + 4]);
        // next x fragments (global, consumed next step)
        const int tn = (t + 1 < TC) ? t + 1 : TC - 1;
        const ushort_t* xph = xhib + (size_t)tn * sT + 8 * q;
        const ushort_t* xpl = xlob + (size_t)tn * sT + 8 * q;
        bf16x8 nh0 = ldbf(xph), nl0 = ldbf(xpl), nh1{}, nl1{};
        if constexpr (KT == 2) { nh1 = ldbf(xph + 32); nl1 = ldbf(xpl + 32); }

        // seed: z_x = bias + Wh.xh + Wh.xl + Wl.xh (3-term; independent of h)
        f32x4 C0 = bias40, C1 = bias41, C2 = bias42, C3 = bias43;
        MFMA(wh00, xh0, C0); MFMA(wh00, xl0, C0); MFMA(wl00, xh0, C0);
        MFMA(wh10, xh0, C1); MFMA(wh10, xl0, C1); MFMA(wl10, xh0, C1);
        MFMA(wh20, xh0, C2); MFMA(wh20, xl0, C2); MFMA(wl20, xh0, C2);
        MFMA(wh30, xh0, C3); MFMA(wh30, xl0, C3); MFMA(wl30, xh0, C3);
        if constexpr (KT == 2) {
            MFMA(wh01, xh1, C0); MFMA(wh01, xl1, C0); MFMA(wl01, xh1, C0);
            MFMA(wh11, xh1, C1); MFMA(wh11, xl1, C1); MFMA(wl11, xh1, C1);
            MFMA(wh21, xh1, C2); MFMA(wh21, xl1, C2); MFMA(wl21, xh1, C2);
            MFMA(wh31, xh1, C3); MFMA(wh31, xl1, C3); MFMA(wl31, xh1, C3);
        }

        // h fragments + U-MFMAs (3-term)
        bf16x8 bh0, bl0, bh1, bl1;
        mkfrag(f0, f1, bh0, bl0);
        mkfrag(f2, f3, bh1, bl1);
        MFMA(uh00, bh0, C0); MFMA(uh00, bl0, C0); MFMA(ul00, bh0, C0);
        MFMA(uh01, bh1, C0); MFMA(uh01, bl1, C0); MFMA(ul01, bh1, C0);
        MFMA(uh10, bh0, C1); MFMA(uh10, bl0, C1); MFMA(ul10, bh0, C1);
        MFMA(uh11, bh1, C1); MFMA(uh11, bl1, C1); MFMA(ul11, bh1, C1);
        MFMA(uh20, bh0, C2); MFMA(uh20, bl0, C2); MFMA(ul20, bh0, C2);
        MFMA(uh21, bh1, C2); MFMA(uh21, bl1, C2); MFMA(ul21, bh1, C2);
        MFMA(uh30, bh0, C3); MFMA(uh30, bl0, C3); MFMA(ul30, bh0, C3);
        MFMA(uh31, bh1, C3); MFMA(uh31, bl1, C3); MFMA(ul31, bh1, C3);

        // online-softmax attention on h_{t-1} (f0..f3; own slice = h4 register, pre-update)
        if (!(first && t == 0)) {
            float sc = 0.f;
#pragma unroll
            for (int i = 0; i < 4; ++i) {
                sc = fmaf(f0[i], wva[i], sc);
                sc = fmaf(f1[i], wvb[i], sc);
                sc = fmaf(f2[i], wvc[i], sc);
                sc = fmaf(f3[i], wvd[i], sc);
            }
            sc += __shfl_xor(sc, 16);
            sc += __shfl_xor(sc, 32);
            float mn = fmaxf(m_b, sc);
            float corr = __expf(m_b - mn);
            float p = __expf(sc - mn);
            d_b = d_b * corr + p;
            acc4 = acc4 * corr + p * h4;
            m_b = mn;
        }

        // activation + state update
#pragma unroll
        for (int i = 0; i < 4; ++i) {
            float zi = sigm(C0[i]);
            float zf = sigm(C1[i]);
            float zg = fmaxf(C2[i], 0.f);
            float zo = sigm(C3[i]);
            c4[i] = fmaf(zf, c4[i], zi * zg);
            h4[i] = zo * fmaxf(c4[i], 0.f);
        }
        st4(&hl[pr ^ 1][r][cw + 4 * q], h4);
        if (Hhi) {   // publish h as hi/lo bf16 planes for the next layer
            int p0 = cvtpk(h4[0], h4[1]), p1 = cvtpk(h4[2], h4[3]);
            float a0 = h4[0] - __int_as_float(p0 << 16);
            float a1 = h4[1] - __int_as_float(p0 & 0xffff0000);
            float a2 = h4[2] - __int_as_float(p1 << 16);
            float a3 = h4[3] - __int_as_float(p1 & 0xffff0000);
            int q0 = cvtpk(a0, a1), q1 = cvtpk(a2, a3);
            size_t ho = (size_t)grow * (TC * HH) + (size_t)t * HH + cw + 4 * q;
            *reinterpret_cast<int2*>(Hhi + ho) = make_int2(p0, p1);
            *reinterpret_cast<int2*>(Hlo + ho) = make_int2(q0, q1);
        }

        xh0 = nh0; xl0 = nl0;
        if constexpr (KT == 2) { xh1 = nh1; xl1 = nl1; }
        __syncthreads();
    }

    // epilogue: last chunk scores h_{TC-1} (in hl[0], TC even) and emits attention output
    if (A.last[seg]) {
        f32x4 f0 = ld4(&hl[0][r][8 * q]);
        f32x4 f1 = ld4(&hl[0][r][8 * q + 4]);
        f32x4 f2 = ld4(&hl[0][r][32 + 8 * q]);
        f32x4 f3 = ld4(&hl[0][r][32 + 8 * q + 4]);
        float sc = 0.f;
#pragma unroll
        for (int i = 0; i < 4; ++i) {
            sc = fmaf(f0[i], wva[i], sc);
            sc = fmaf(f1[i], wvb[i], sc);
            sc = fmaf(f2[i], wvc[i], sc);
            sc = fmaf(f3[i], wvd[i], sc);
        }
        sc += __shfl_xor(sc, 16);
        sc += __shfl_xor(sc, 32);
        float mn = fmaxf(m_b, sc);
        float corr = __expf(m_b - mn);
        float p = __expf(sc - mn);
        d_b = d_b * corr + p;
        acc4 = acc4 * corr + p * h4;
        m_b = mn;
        f32x4 sb = ld4(A.sbn[seg] + cw + 4 * q);
        f32x4 ab = ld4(A.abv[seg] + cw + 4 * q);
        f32x4 res;
#pragma unroll
        for (int i = 0; i < 4; ++i)
            res[i] = sb[i] * __fdividef(acc4[i], d_b) + ab[i];
        st4(A.a_out[seg] + (size_t)grow * HH + cw + 4 * q, res);
    }
    st4(A.st_c[seg]   + (size_t)grow * HH + cw + 4 * q, c4);
    st4(A.st_h[seg]   + (size_t)grow * HH + cw + 4 * q, h4);
    st4(A.st_acc[seg] + (size_t)grow * HH + cw + 4 * q, acc4);
    if (w == 0 && q == 0) { A.st_m[seg][grow] = m_b; A.st_d[seg][grow] = d_b; }
#undef LDU
#undef LDW
}

__global__ __launch_bounds__(512, 1) void rec_mfma(RecFArgs A) {
    __shared__ float hl[2][2][MB][HPAD];          // per-group parity-dbuf h, 17.4 KB
    const int seg = blockIdx.x >> 5;              // NBLK2 = 32 blocks/segment
    const int grp = threadIdx.x >> 8;             // 0 or 1
    const int b0 = ((blockIdx.x & (NBLK2 - 1)) << 5) + (grp << 4);
    const int tid = threadIdx.x & 255;
    if (A.K[seg] == 32) rec_body<1>(A, seg, b0, tid, hl[grp]);
    else                rec_body<2>(A, seg, b0, tid, hl[grp]);
}

// ---------------- final: out[b] = db + sum_{l,j} a[l][b][j]*dw[l*64+j] ----------------
__global__ void final_kernel(const float* __restrict__ a, const float* __restrict__ dw,
                             const float* __restrict__ db, float* __restrict__ out) {
    int b = blockIdx.x * blockDim.x + threadIdx.x;
    if (b >= BB) return;
    float acc = db[0];
    for (int l = 0; l < 3; ++l)
        for (int j = 0; j < HH; ++j)
            acc += a[(l * BB + b) * HH + j] * dw[l * HH + j];
    out[b] = acc;
}

extern "C" void kernel_launch(void* const* d_in, const int* in_sizes, int n_in,
                              void* d_out, int out_size, void* d_ws, size_t ws_size,
                              hipStream_t stream) {
    (void)in_sizes; (void)n_in; (void)out_size; (void)ws_size;
    const float* x = (const float*)d_in[0];
    const float* w[3]    = {(const float*)d_in[1],  (const float*)d_in[10], (const float*)d_in[19]};
    const float* uu[3]   = {(const float*)d_in[2],  (const float*)d_in[11], (const float*)d_in[20]};
    const float* bi[3]   = {(const float*)d_in[3],  (const float*)d_in[12], (const float*)d_in[21]};
    const float* gam[3]  = {(const float*)d_in[4],  (const float*)d_in[13], (const float*)d_in[22]};
    const float* bet[3]  = {(const float*)d_in[5],  (const float*)d_in[14], (const float*)d_in[23]};
    const float* mea[3]  = {(const float*)d_in[6],  (const float*)d_in[15], (const float*)d_in[24]};
    const float* var[3]  = {(const float*)d_in[7],  (const float*)d_in[16], (const float*)d_in[25]};
    const float* atw[3]  = {(const float*)d_in[8],  (const float*)d_in[17], (const float*)d_in[26]};
    const float* atv[3]  = {(const float*)d_in[9],  (const float*)d_in[18], (const float*)d_in[27]};
    const float* dw = (const float*)d_in[28];
    const float* db = (const float*)d_in[29];

    float* ws = (float*)d_ws;
    size_t off = 0;
    // cross-layer h planes (bf16 hi/lo), parity double-buffered
    ushort_t* Hhi[2][2]; ushort_t* Hlo[2][2];
    for (int l = 0; l < 2; ++l)
        for (int p = 0; p < 2; ++p) {
            Hhi[l][p] = (ushort_t*)(ws + off); off += (size_t)BB * TC * HH / 2;
            Hlo[l][p] = (ushort_t*)(ws + off); off += (size_t)BB * TC * HH / 2;
        }
    // layer-1 input planes (bf16 hi/lo)
    ushort_t* Xhi = (ushort_t*)(ws + off); off += (size_t)BB * TT * FF / 2;
    ushort_t* Xlo = (ushort_t*)(ws + off); off += (size_t)BB * TT * FF / 2;
    float* st_h  = ws + off; off += 3 * BB * HH;
    float* st_c  = ws + off; off += 3 * BB * HH;
    float* st_ac = ws + off; off += 3 * BB * HH;
    float* st_m  = ws + off; off += 3 * BB;
    float* st_d  = ws + off; off += 3 * BB;
    float* s_ws  = ws + off; off += 3 * HH;
    float* ab_ws = ws + off; off += 3 * HH;
    float* wv_ws = ws + off; off += 3 * HH;
    float* W2p   = ws + off; off += HH * GG;
    float* W3p   = ws + off; off += HH * GG;
    float* b2p   = ws + off; off += GG;
    float* b3p   = ws + off; off += GG;
    float* a_ws  = ws + off; off += 3 * BB * HH;
    ushort_t* UFb[3]; ushort_t* WFb[3];
    for (int l = 0; l < 3; ++l) { UFb[l] = (ushort_t*)(ws + off); off += 16384; }  // 64KB each
    for (int l = 0; l < 3; ++l) { WFb[l] = (ushort_t*)(ws + off); off += 16384; }

    for (int l = 0; l < 3; ++l)
        fold1_kernel<<<1, 64, 0, stream>>>(gam[l], bet[l], mea[l], var[l], atw[l], atv[l],
                                           s_ws + l * HH, ab_ws + l * HH, wv_ws + l * HH);
    fold2_kernel<<<1, 256, 0, stream>>>(w[1], bi[1], s_ws + 0 * HH, ab_ws + 0 * HH, W2p, b2p);
    fold2_kernel<<<1, 256, 0, stream>>>(w[2], bi[2], s_ws + 1 * HH, ab_ws + 1 * HH, W3p, b3p);
    init_kernel<<<(3 * BB * HH + 255) / 256, 256, 0, stream>>>(st_h, st_c, st_ac, st_m, st_d);

    // pre-build bf16 weight fragments and x planes
    for (int l = 0; l < 3; ++l)
        prep_frags<<<64, 256, 0, stream>>>(uu[l], 2, UFb[l]);
    prep_frags<<<32, 256, 0, stream>>>(w[0], 1, WFb[0]);
    prep_frags<<<64, 256, 0, stream>>>(W2p, 2, WFb[1]);
    prep_frags<<<64, 256, 0, stream>>>(W3p, 2, WFb[2]);
    {
        int n4 = BB * TT * FF / 4;
        prep_planes<<<(n4 + 255) / 256, 256, 0, stream>>>(x, Xhi, Xlo, n4);
    }

    const float* bl[3] = {bi[0], b2p, b3p};

    // software pipeline: at step s, layer l processes chunk s-l
    for (int s = 0; s <= NCHUNK - 1 + 2; ++s) {
        RecFArgs ra;
        int nseg = 0;
        for (int l = 0; l < 3; ++l) {
            int cpos = s - l;
            if (cpos < 0 || cpos >= NCHUNK) continue;
            if (l == 0) {
                ra.xhi[nseg] = Xhi + (size_t)cpos * TC * FF;
                ra.xlo[nseg] = Xlo + (size_t)cpos * TC * FF;
                ra.sB[nseg] = (long)TT * FF;
                ra.sT[nseg] = FF;
                ra.K[nseg] = 32;
            } else {
                int par = (s & 1) ^ 1;               // written by layer l-1 at step s-1
                ra.xhi[nseg] = Hhi[l - 1][par];
                ra.xlo[nseg] = Hlo[l - 1][par];
                ra.sB[nseg] = (long)TC * HH;
                ra.sT[nseg] = HH;
                ra.K[nseg] = 64;
            }
            ra.UF[nseg] = UFb[l]; ra.WF[nseg] = WFb[l]; ra.bias[nseg] = bl[l];
            ra.Hhi[nseg] = (l < 2) ? Hhi[l][s & 1] : (ushort_t*)0;
            ra.Hlo[nseg] = (l < 2) ? Hlo[l][s & 1] : (ushort_t*)0;
            ra.st_h[nseg] = st_h + l * BB * HH;
            ra.st_c[nseg] = st_c + l * BB * HH;
            ra.st_acc[nseg] = st_ac + l * BB * HH;
            ra.st_m[nseg] = st_m + l * BB;
            ra.st_d[nseg] = st_d + l * BB;
            ra.wv[nseg]  = wv_ws + l * HH;
            ra.abv[nseg] = ab_ws + l * HH;
            ra.sbn[nseg] = s_ws + l * HH;
            ra.a_out[nseg] = a_ws + l * BB * HH;
            ra.last[nseg]  = (cpos == NCHUNK - 1) ? 1 : 0;
            ra.first[nseg] = (cpos == 0) ? 1 : 0;
            ++nseg;
        }
        if (!nseg) continue;
        rec_mfma<<<nseg * NBLK2, 512, 0, stream>>>(ra);
    }
    final_kernel<<<(BB + 255) / 256, 256, 0, stream>>>(a_ws, dw, db, (float*)d_out);
}

// Round 13
// 848.236 us; speedup vs baseline: 1.4845x; 1.4845x over previous
//
#include <hip/hip_runtime.h>
#include <math.h>

#define BB 1024
#define TT 512
#define FF 32
#define HH 64
#define GG 256   // 4H
#define TC 64
#define NCHUNK (TT/TC)   // 8
#define MB 16            // batch rows per block
#define NBLK 64          // blocks per segment
#define HSTR 72          // ushort row stride in LDS h-planes (144B -> 2-way banks)
#define EPSBN 1e-3f

typedef __attribute__((ext_vector_type(8))) short bf16x8;
typedef __attribute__((ext_vector_type(4))) float f32x4;
typedef __attribute__((ext_vector_type(4))) int   i32x4;
typedef unsigned short ushort_t;

// ---------------- fold1: per-layer BN vectors + attention vector ----------------
__global__ void fold1_kernel(const float* __restrict__ gamma, const float* __restrict__ beta,
                             const float* __restrict__ mean, const float* __restrict__ var,
                             const float* __restrict__ attw, const float* __restrict__ attv,
                             float* __restrict__ s_out, float* __restrict__ ab_out,
                             float* __restrict__ wv_out) {
    int d = threadIdx.x; // 64 threads
    float s = gamma[d] * rsqrtf(var[d] + EPSBN);
    float ab = beta[d] - mean[d] * s;
    float wvr = 0.f;
    for (int e = 0; e < HH; ++e) wvr += attw[d * HH + e] * attv[e];
    s_out[d] = s;
    ab_out[d] = ab;
    wv_out[d] = s * wvr;
}

// ---------------- fold2: fold previous layer's BN into next W, b ----------------
__global__ void fold2_kernel(const float* __restrict__ W, const float* __restrict__ b,
                             const float* __restrict__ s_prev, const float* __restrict__ ab_prev,
                             float* __restrict__ Wp, float* __restrict__ bp) {
    int g = threadIdx.x; // 256 threads
    float bacc = b[g];
    for (int d = 0; d < HH; ++d) {
        float w = W[d * GG + g];
        bacc += ab_prev[d] * w;
        Wp[d * GG + g] = s_prev[d] * w;
    }
    bp[g] = bacc;
}

// ---------------- init per-call state ----------------
__global__ void init_kernel(float* st_h, float* st_c, float* st_acc, float* st_m, float* st_d) {
    int i = blockIdx.x * blockDim.x + threadIdx.x;
    int n = 3 * BB * HH;
    if (i < n) { st_h[i] = 0.f; st_c[i] = 0.f; st_acc[i] = 0.f; }
    if (i < 3 * BB) { st_m[i] = -3.0e38f; st_d[i] = 0.f; }
}

// ---------------- helpers ----------------
__device__ __forceinline__ f32x4 ld4(const float* p) { return *reinterpret_cast<const f32x4*>(p); }
__device__ __forceinline__ void st4(float* p, f32x4 v) { *reinterpret_cast<f32x4*>(p) = v; }
__device__ __forceinline__ bf16x8 ldbf(const ushort_t* p) { return *reinterpret_cast<const bf16x8*>(p); }
__device__ __forceinline__ int cvtpk(float a, float b) {
    int r; asm("v_cvt_pk_bf16_f32 %0, %1, %2" : "=v"(r) : "v"(a), "v"(b)); return r;
}
__device__ __forceinline__ float sigm(float x) { return __fdividef(1.f, 1.f + __expf(-x)); }
#define MFMA(a, b, c) c = __builtin_amdgcn_mfma_f32_16x16x32_bf16(a, b, c, 0, 0, 0)

// ---------------- prep: fp32 weight matrix -> hi/lo bf16 A-fragments, per-lane layout ----
__global__ void prep_frags(const float* __restrict__ M, int KT, ushort_t* __restrict__ outF) {
    int idx = blockIdx.x * 256 + threadIdx.x;
    int tot = 16 * KT * 512;
    if (idx >= tot) return;
    int e = idx & 7, l = (idx >> 3) & 63, f = idx >> 9;
    int kt = f % KT, gw = f / KT;
    int g = gw & 3, w = gw >> 2;
    int r = l & 15, q = l >> 4;
    int k = 32 * kt + 8 * q + e;
    int col = 64 * g + 16 * w + r;
    float v = M[(size_t)k * GG + col];
    int hb = cvtpk(v, v) & 0xffff;
    float hf = __int_as_float(hb << 16);
    float lo = v - hf;
    int lb = cvtpk(lo, lo) & 0xffff;
    outF[(size_t)(f * 2 + 0) * 512 + l * 8 + e] = (ushort_t)hb;
    outF[(size_t)(f * 2 + 1) * 512 + l * 8 + e] = (ushort_t)lb;
}

// ---------------- prep: fp32 array -> hi/lo bf16 planes (elementwise, vectorized) ----
__global__ void prep_planes(const float* __restrict__ in, ushort_t* __restrict__ hi,
                            ushort_t* __restrict__ lo, int n4) {
    int i = blockIdx.x * 256 + threadIdx.x;
    if (i >= n4) return;
    f32x4 v = reinterpret_cast<const f32x4*>(in)[i];
    int p0 = cvtpk(v[0], v[1]), p1 = cvtpk(v[2], v[3]);
    float a0 = v[0] - __int_as_float(p0 << 16);
    float a1 = v[1] - __int_as_float(p0 & 0xffff0000);
    float a2 = v[2] - __int_as_float(p1 << 16);
    float a3 = v[3] - __int_as_float(p1 & 0xffff0000);
    int q0 = cvtpk(a0, a1), q1 = cvtpk(a2, a3);
    reinterpret_cast<int2*>(hi)[i] = make_int2(p0, p1);
    reinterpret_cast<int2*>(lo)[i] = make_int2(q0, q1);
}

// ---------------- MFMA recurrent kernel: bf16 LDS h-planes, deferred stores ----------------
// Block = 16 rows, 4 waves. Wave w owns gate-cols {64g+16w+..}; lane (r,q) holds all 4
// gates of (row r, units 16w+4q..+4) -> in-lane c/h update. h feedback published as bf16
// hi/lo planes in LDS (each wave converts only its own slice); B-fragments read directly
// (no in-loop mkfrag; 2-way banks = free). Hout global stores deferred one step (retire
// under MFMAs -> no vmcnt drain at barrier). Attention: per-wave 4-fma partial + LDS
// exchange, lag-one (r7 pattern). One barrier per step.
struct RecFArgs {
    const ushort_t* xhi[3]; const ushort_t* xlo[3]; long sB[3]; long sT[3]; int K[3];
    const ushort_t* UF[3]; const ushort_t* WF[3]; const float* bias[3];
    ushort_t* Hhi[3]; ushort_t* Hlo[3];   // nullptr -> skip
    float* st_h[3]; float* st_c[3]; float* st_acc[3];
    float* st_m[3]; float* st_d[3];
    const float* wv[3]; const float* abv[3]; const float* sbn[3];
    float* a_out[3];
    int last[3]; int first[3];
};

template<int KT>   // x K-tiles: 1 (K=32, layer1) or 2 (K=64)
__device__ __forceinline__ void rec_body(const RecFArgs& A, const int seg, const int b0,
                                         ushort_t* hbf, float* scoreP) {
    const int tid = threadIdx.x;
    const int w = tid >> 6;
    const int l = tid & 63;
    const int r = l & 15;
    const int q = l >> 4;
    const int cw = w << 4;
    const int grow = b0 + r;

    const bf16x8* UF = reinterpret_cast<const bf16x8*>(A.UF[seg]);
    const bf16x8* WF = reinterpret_cast<const bf16x8*>(A.WF[seg]);
#define LDU(g,kt,p_) UF[(((((w<<2)+(g))*2+(kt))*2)+(p_))*64 + l]
#define LDW(g,kt,p_) WF[(((((w<<2)+(g))*KT+(kt))*2)+(p_))*64 + l]
    bf16x8 uh00=LDU(0,0,0), uh01=LDU(0,1,0), uh10=LDU(1,0,0), uh11=LDU(1,1,0),
           uh20=LDU(2,0,0), uh21=LDU(2,1,0), uh30=LDU(3,0,0), uh31=LDU(3,1,0);
    bf16x8 ul00=LDU(0,0,1), ul01=LDU(0,1,1), ul10=LDU(1,0,1), ul11=LDU(1,1,1),
           ul20=LDU(2,0,1), ul21=LDU(2,1,1), ul30=LDU(3,0,1), ul31=LDU(3,1,1);
    bf16x8 wh00=LDW(0,0,0), wh10=LDW(1,0,0), wh20=LDW(2,0,0), wh30=LDW(3,0,0);
    bf16x8 wl00=LDW(0,0,1), wl10=LDW(1,0,1), wl20=LDW(2,0,1), wl30=LDW(3,0,1);
    bf16x8 wh01{}, wh11{}, wh21{}, wh31{}, wl01{}, wl11{}, wl21{}, wl31{};
    if constexpr (KT == 2) {
        wh01=LDW(0,1,0); wh11=LDW(1,1,0); wh21=LDW(2,1,0); wh31=LDW(3,1,0);
        wl01=LDW(0,1,1); wl11=LDW(1,1,1); wl21=LDW(2,1,1); wl31=LDW(3,1,1);
    }

    f32x4 bias40 = ld4(A.bias[seg] +   0 + cw + 4 * q);
    f32x4 bias41 = ld4(A.bias[seg] +  64 + cw + 4 * q);
    f32x4 bias42 = ld4(A.bias[seg] + 128 + cw + 4 * q);
    f32x4 bias43 = ld4(A.bias[seg] + 192 + cw + 4 * q);
    f32x4 wv4 = ld4(A.wv[seg] + cw + 4 * q);      // own 4 units only

    f32x4 c4   = ld4(A.st_c[seg]   + (size_t)grow * HH + cw + 4 * q);
    f32x4 h4   = ld4(A.st_h[seg]   + (size_t)grow * HH + cw + 4 * q);
    f32x4 acc4 = ld4(A.st_acc[seg] + (size_t)grow * HH + cw + 4 * q);
    float m_b = A.st_m[seg][grow];
    float d_b = A.st_d[seg][grow];

    int2 hs_hi, hs_lo;     // h planes of previous step (deferred global store)
    // publish: convert own slice -> LDS planes + score partial (slot, value)
    auto publish = [&](int slot, f32x4 hv) {
        int p0 = cvtpk(hv[0], hv[1]), p1 = cvtpk(hv[2], hv[3]);
        float a0 = hv[0] - __int_as_float(p0 << 16);
        float a1 = hv[1] - __int_as_float(p0 & 0xffff0000);
        float a2 = hv[2] - __int_as_float(p1 << 16);
        float a3 = hv[3] - __int_as_float(p1 & 0xffff0000);
        int q0 = cvtpk(a0, a1), q1 = cvtpk(a2, a3);
        hs_hi = make_int2(p0, p1); hs_lo = make_int2(q0, q1);
        *reinterpret_cast<int2*>(hbf + ((slot * 2 + 0) * 16 + r) * HSTR + cw + 4 * q) = hs_hi;
        *reinterpret_cast<int2*>(hbf + ((slot * 2 + 1) * 16 + r) * HSTR + cw + 4 * q) = hs_lo;
        float part = hv[0] * wv4[0];
        part = fmaf(hv[1], wv4[1], part);
        part = fmaf(hv[2], wv4[2], part);
        part = fmaf(hv[3], wv4[3], part);
        part += __shfl_xor(part, 16);
        part += __shfl_xor(part, 32);
        if (q == 0) scoreP[(slot * 4 + w) * 16 + r] = part;
    };

    publish(0, h4);   // carried h -> slot 0 (consumed at t=0)

    const ushort_t* xhib = A.xhi[seg] + (size_t)grow * A.sB[seg];
    const ushort_t* xlob = A.xlo[seg] + (size_t)grow * A.sB[seg];
    const long sT = A.sT[seg];

    bf16x8 xh0 = ldbf(xhib + 8 * q), xl0 = ldbf(xlob + 8 * q);
    bf16x8 xh1{}, xl1{};
    if constexpr (KT == 2) { xh1 = ldbf(xhib + 32 + 8 * q); xl1 = ldbf(xlob + 32 + 8 * q); }
    __syncthreads();

    const bool first = A.first[seg] != 0;
    ushort_t* Hhi = A.Hhi[seg];
    ushort_t* Hlo = A.Hlo[seg];

#pragma unroll 2
    for (int t = 0; t < TC; ++t) {
        const int pr = t & 1;
        // deferred Hout store of h_{t-1} (retires under this step's MFMAs)
        if (Hhi && t > 0) {
            size_t ho = (size_t)grow * (TC * HH) + (size_t)(t - 1) * HH + cw + 4 * q;
            *reinterpret_cast<int2*>(Hhi + ho) = hs_hi;
            *reinterpret_cast<int2*>(Hlo + ho) = hs_lo;
        }
        // attention merge for h_{t-1} (score from LDS partials; vector from h4 regs)
        float sc = scoreP[(pr * 4 + q) * 16 + r];
        sc += __shfl_xor(sc, 16);
        sc += __shfl_xor(sc, 32);
        if (!(first && t == 0)) {
            float mn = fmaxf(m_b, sc);
            float corr = __expf(m_b - mn);
            float p = __expf(sc - mn);
            d_b = d_b * corr + p;
            acc4 = acc4 * corr + p * h4;
            m_b = mn;
        }
        // prefetch next x fragments (bf16 planes, no conversion needed)
        const int tn = (t + 1 < TC) ? t + 1 : TC - 1;
        const ushort_t* xph = xhib + (size_t)tn * sT + 8 * q;
        const ushort_t* xpl = xlob + (size_t)tn * sT + 8 * q;
        bf16x8 nh0 = ldbf(xph), nl0 = ldbf(xpl), nh1{}, nl1{};
        if constexpr (KT == 2) { nh1 = ldbf(xph + 32); nl1 = ldbf(xpl + 32); }

        // B-fragments of h_{t-1}: direct bf16 reads (2-way banks, broadcast-ish)
        const ushort_t* hbh = hbf + (pr * 2 + 0) * 16 * HSTR + r * HSTR;
        const ushort_t* hbl = hbf + (pr * 2 + 1) * 16 * HSTR + r * HSTR;
        bf16x8 bh0 = ldbf(hbh + 8 * q);
        bf16x8 bh1 = ldbf(hbh + 32 + 8 * q);
        bf16x8 bl0 = ldbf(hbl + 8 * q);
        bf16x8 bl1 = ldbf(hbl + 32 + 8 * q);

        // gate 0 (accumulation order identical to r12)
        f32x4 C0 = bias40;
        MFMA(wh00, xh0, C0); MFMA(wh00, xl0, C0); MFMA(wl00, xh0, C0);
        if constexpr (KT == 2) { MFMA(wh01, xh1, C0); MFMA(wh01, xl1, C0); MFMA(wl01, xh1, C0); }
        MFMA(uh00, bh0, C0); MFMA(uh00, bl0, C0); MFMA(ul00, bh0, C0);
        MFMA(uh01, bh1, C0); MFMA(uh01, bl1, C0); MFMA(ul01, bh1, C0);
        // gate 1
        f32x4 C1 = bias41;
        MFMA(wh10, xh0, C1); MFMA(wh10, xl0, C1); MFMA(wl10, xh0, C1);
        if constexpr (KT == 2) { MFMA(wh11, xh1, C1); MFMA(wh11, xl1, C1); MFMA(wl11, xh1, C1); }
        MFMA(uh10, bh0, C1); MFMA(uh10, bl0, C1); MFMA(ul10, bh0, C1);
        MFMA(uh11, bh1, C1); MFMA(uh11, bl1, C1); MFMA(ul11, bh1, C1);
        // gate 2
        f32x4 C2 = bias42;
        MFMA(wh20, xh0, C2); MFMA(wh20, xl0, C2); MFMA(wl20, xh0, C2);
        if constexpr (KT == 2) { MFMA(wh21, xh1, C2); MFMA(wh21, xl1, C2); MFMA(wl21, xh1, C2); }
        MFMA(uh20, bh0, C2); MFMA(uh20, bl0, C2); MFMA(ul20, bh0, C2);
        MFMA(uh21, bh1, C2); MFMA(uh21, bl1, C2); MFMA(ul21, bh1, C2);
        // gate 3
        f32x4 C3 = bias43;
        MFMA(wh30, xh0, C3); MFMA(wh30, xl0, C3); MFMA(wl30, xh0, C3);
        if constexpr (KT == 2) { MFMA(wh31, xh1, C3); MFMA(wh31, xl1, C3); MFMA(wl31, xh1, C3); }
        MFMA(uh30, bh0, C3); MFMA(uh30, bl0, C3); MFMA(ul30, bh0, C3);
        MFMA(uh31, bh1, C3); MFMA(uh31, bl1, C3); MFMA(ul31, bh1, C3);

        // activation + state update
#pragma unroll
        for (int i = 0; i < 4; ++i) {
            float zi = sigm(C0[i]);
            float zf = sigm(C1[i]);
            float zg = fmaxf(C2[i], 0.f);
            float zo = sigm(C3[i]);
            c4[i] = fmaf(zf, c4[i], zi * zg);
            h4[i] = zo * fmaxf(c4[i], 0.f);
        }
        publish(pr ^ 1, h4);   // planes + score partial for next step

        xh0 = nh0; xl0 = nl0;
        if constexpr (KT == 2) { xh1 = nh1; xl1 = nl1; }
        __syncthreads();
    }

    // post-loop: final Hout store of h_{TC-1}
    if (Hhi) {
        size_t ho = (size_t)grow * (TC * HH) + (size_t)(TC - 1) * HH + cw + 4 * q;
        *reinterpret_cast<int2*>(Hhi + ho) = hs_hi;
        *reinterpret_cast<int2*>(Hlo + ho) = hs_lo;
    }
    // last chunk: merge h_{TC-1}'s score (slot (TC)&1 == 0) and emit attention output
    if (A.last[seg]) {
        float sc = scoreP[(0 * 4 + q) * 16 + r];
        sc += __shfl_xor(sc, 16);
        sc += __shfl_xor(sc, 32);
        float mn = fmaxf(m_b, sc);
        float corr = __expf(m_b - mn);
        float p = __expf(sc - mn);
        d_b = d_b * corr + p;
        acc4 = acc4 * corr + p * h4;
        m_b = mn;
        f32x4 sb = ld4(A.sbn[seg] + cw + 4 * q);
        f32x4 ab = ld4(A.abv[seg] + cw + 4 * q);
        f32x4 res;
#pragma unroll
        for (int i = 0; i < 4; ++i)
            res[i] = sb[i] * __fdividef(acc4[i], d_b) + ab[i];
        st4(A.a_out[seg] + (size_t)grow * HH + cw + 4 * q, res);
    }
    st4(A.st_c[seg]   + (size_t)grow * HH + cw + 4 * q, c4);
    st4(A.st_h[seg]   + (size_t)grow * HH + cw + 4 * q, h4);
    st4(A.st_acc[seg] + (size_t)grow * HH + cw + 4 * q, acc4);
    if (w == 0 && q == 0) { A.st_m[seg][grow] = m_b; A.st_d[seg][grow] = d_b; }
#undef LDU
#undef LDW
}

__global__ __launch_bounds__(256, 2) void rec_mfma(RecFArgs A) {
    __shared__ ushort_t hbf[2 * 2 * 16 * HSTR];   // 9.2 KB: parity x {hi,lo} x [16][72]
    __shared__ float scoreP[2 * 4 * 16];          // 512 B: parity x wave x row
    const int seg = blockIdx.x >> 6;              // NBLK = 64
    const int b0 = (blockIdx.x & (NBLK - 1)) << 4;
    if (A.K[seg] == 32) rec_body<1>(A, seg, b0, hbf, scoreP);
    else                rec_body<2>(A, seg, b0, hbf, scoreP);
}

// ---------------- final: out[b] = db + sum_{l,j} a[l][b][j]*dw[l*64+j] ----------------
__global__ void final_kernel(const float* __restrict__ a, const float* __restrict__ dw,
                             const float* __restrict__ db, float* __restrict__ out) {
    int b = blockIdx.x * blockDim.x + threadIdx.x;
    if (b >= BB) return;
    float acc = db[0];
    for (int l = 0; l < 3; ++l)
        for (int j = 0; j < HH; ++j)
            acc += a[(l * BB + b) * HH + j] * dw[l * HH + j];
    out[b] = acc;
}

extern "C" void kernel_launch(void* const* d_in, const int* in_sizes, int n_in,
                              void* d_out, int out_size, void* d_ws, size_t ws_size,
                              hipStream_t stream) {
    (void)in_sizes; (void)n_in; (void)out_size; (void)ws_size;
    const float* x = (const float*)d_in[0];
    const float* w[3]    = {(const float*)d_in[1],  (const float*)d_in[10], (const float*)d_in[19]};
    const float* uu[3]   = {(const float*)d_in[2],  (const float*)d_in[11], (const float*)d_in[20]};
    const float* bi[3]   = {(const float*)d_in[3],  (const float*)d_in[12], (const float*)d_in[21]};
    const float* gam[3]  = {(const float*)d_in[4],  (const float*)d_in[13], (const float*)d_in[22]};
    const float* bet[3]  = {(const float*)d_in[5],  (const float*)d_in[14], (const float*)d_in[23]};
    const float* mea[3]  = {(const float*)d_in[6],  (const float*)d_in[15], (const float*)d_in[24]};
    const float* var[3]  = {(const float*)d_in[7],  (const float*)d_in[16], (const float*)d_in[25]};
    const float* atw[3]  = {(const float*)d_in[8],  (const float*)d_in[17], (const float*)d_in[26]};
    const float* atv[3]  = {(const float*)d_in[9],  (const float*)d_in[18], (const float*)d_in[27]};
    const float* dw = (const float*)d_in[28];
    const float* db = (const float*)d_in[29];

    float* ws = (float*)d_ws;
    size_t off = 0;
    // cross-layer h planes (bf16 hi/lo), parity double-buffered
    ushort_t* Hhi[2][2]; ushort_t* Hlo[2][2];
    for (int l = 0; l < 2; ++l)
        for (int p = 0; p < 2; ++p) {
            Hhi[l][p] = (ushort_t*)(ws + off); off += (size_t)BB * TC * HH / 2;
            Hlo[l][p] = (ushort_t*)(ws + off); off += (size_t)BB * TC * HH / 2;
        }
    // layer-1 input planes (bf16 hi/lo)
    ushort_t* Xhi = (ushort_t*)(ws + off); off += (size_t)BB * TT * FF / 2;
    ushort_t* Xlo = (ushort_t*)(ws + off); off += (size_t)BB * TT * FF / 2;
    float* st_h  = ws + off; off += 3 * BB * HH;
    float* st_c  = ws + off; off += 3 * BB * HH;
    float* st_ac = ws + off; off += 3 * BB * HH;
    float* st_m  = ws + off; off += 3 * BB;
    float* st_d  = ws + off; off += 3 * BB;
    float* s_ws  = ws + off; off += 3 * HH;
    float* ab_ws = ws + off; off += 3 * HH;
    float* wv_ws = ws + off; off += 3 * HH;
    float* W2p   = ws + off; off += HH * GG;
    float* W3p   = ws + off; off += HH * GG;
    float* b2p   = ws + off; off += GG;
    float* b3p   = ws + off; off += GG;
    float* a_ws  = ws + off; off += 3 * BB * HH;
    ushort_t* UFb[3]; ushort_t* WFb[3];
    for (int l = 0; l < 3; ++l) { UFb[l] = (ushort_t*)(ws + off); off += 16384; }  // 64KB each
    for (int l = 0; l < 3; ++l) { WFb[l] = (ushort_t*)(ws + off); off += 16384; }

    for (int l = 0; l < 3; ++l)
        fold1_kernel<<<1, 64, 0, stream>>>(gam[l], bet[l], mea[l], var[l], atw[l], atv[l],
                                           s_ws + l * HH, ab_ws + l * HH, wv_ws + l * HH);
    fold2_kernel<<<1, 256, 0, stream>>>(w[1], bi[1], s_ws + 0 * HH, ab_ws + 0 * HH, W2p, b2p);
    fold2_kernel<<<1, 256, 0, stream>>>(w[2], bi[2], s_ws + 1 * HH, ab_ws + 1 * HH, W3p, b3p);
    init_kernel<<<(3 * BB * HH + 255) / 256, 256, 0, stream>>>(st_h, st_c, st_ac, st_m, st_d);

    // pre-build bf16 weight fragments and x planes
    for (int l = 0; l < 3; ++l)
        prep_frags<<<64, 256, 0, stream>>>(uu[l], 2, UFb[l]);
    prep_frags<<<32, 256, 0, stream>>>(w[0], 1, WFb[0]);
    prep_frags<<<64, 256, 0, stream>>>(W2p, 2, WFb[1]);
    prep_frags<<<64, 256, 0, stream>>>(W3p, 2, WFb[2]);
    {
        int n4 = BB * TT * FF / 4;
        prep_planes<<<(n4 + 255) / 256, 256, 0, stream>>>(x, Xhi, Xlo, n4);
    }

    const float* bl[3] = {bi[0], b2p, b3p};

    // software pipeline: at step s, layer l processes chunk s-l
    for (int s = 0; s <= NCHUNK - 1 + 2; ++s) {
        RecFArgs ra;
        int nseg = 0;
        for (int l = 0; l < 3; ++l) {
            int cpos = s - l;
            if (cpos < 0 || cpos >= NCHUNK) continue;
            if (l == 0) {
                ra.xhi[nseg] = Xhi + (size_t)cpos * TC * FF;
                ra.xlo[nseg] = Xlo + (size_t)cpos * TC * FF;
                ra.sB[nseg] = (long)TT * FF;
                ra.sT[nseg] = FF;
                ra.K[nseg] = 32;
            } else {
                int par = (s & 1) ^ 1;               // written by layer l-1 at step s-1
                ra.xhi[nseg] = Hhi[l - 1][par];
                ra.xlo[nseg] = Hlo[l - 1][par];
                ra.sB[nseg] = (long)TC * HH;
                ra.sT[nseg] = HH;
                ra.K[nseg] = 64;
            }
            ra.UF[nseg] = UFb[l]; ra.WF[nseg] = WFb[l]; ra.bias[nseg] = bl[l];
            ra.Hhi[nseg] = (l < 2) ? Hhi[l][s & 1] : (ushort_t*)0;
            ra.Hlo[nseg] = (l < 2) ? Hlo[l][s & 1] : (ushort_t*)0;
            ra.st_h[nseg] = st_h + l * BB * HH;
            ra.st_c[nseg] = st_c + l * BB * HH;
            ra.st_acc[nseg] = st_ac + l * BB * HH;
            ra.st_m[nseg] = st_m + l * BB;
            ra.st_d[nseg] = st_d + l * BB;
            ra.wv[nseg]  = wv_ws + l * HH;
            ra.abv[nseg] = ab_ws + l * HH;
            ra.sbn[nseg] = s_ws + l * HH;
            ra.a_out[nseg] = a_ws + l * BB * HH;
            ra.last[nseg]  = (cpos == NCHUNK - 1) ? 1 : 0;
            ra.first[nseg] = (cpos == 0) ? 1 : 0;
            ++nseg;
        }
        if (!nseg) continue;
        rec_mfma<<<nseg * NBLK, 256, 0, stream>>>(ra);
    }
    final_kernel<<<(BB + 255) / 256, 256, 0, stream>>>(a_ws, dw, db, (float*)d_out);
}

// Round 14
// 761.495 us; speedup vs baseline: 1.6536x; 1.1139x over previous
//
#include <hip/hip_runtime.h>
#include <math.h>

#define BB 1024
#define TT 512
#define FF 32
#define HH 64
#define GG 256   // 4H
#define TC 64
#define NCHUNK (TT/TC)   // 8
#define MB 16            // batch rows per block
#define NBLK 64          // blocks per segment
#define HSTR 72          // ushort row stride in LDS h-planes (144B -> 2-way banks)
#define EPSBN 1e-3f

typedef __attribute__((ext_vector_type(8))) short bf16x8;
typedef __attribute__((ext_vector_type(4))) float f32x4;
typedef __attribute__((ext_vector_type(4))) int   i32x4;
typedef unsigned short ushort_t;

// ---------------- fold1: per-layer BN vectors + attention vector ----------------
__global__ void fold1_kernel(const float* __restrict__ gamma, const float* __restrict__ beta,
                             const float* __restrict__ mean, const float* __restrict__ var,
                             const float* __restrict__ attw, const float* __restrict__ attv,
                             float* __restrict__ s_out, float* __restrict__ ab_out,
                             float* __restrict__ wv_out) {
    int d = threadIdx.x; // 64 threads
    float s = gamma[d] * rsqrtf(var[d] + EPSBN);
    float ab = beta[d] - mean[d] * s;
    float wvr = 0.f;
    for (int e = 0; e < HH; ++e) wvr += attw[d * HH + e] * attv[e];
    s_out[d] = s;
    ab_out[d] = ab;
    wv_out[d] = s * wvr;
}

// ---------------- fold2: fold previous layer's BN into next W, b ----------------
__global__ void fold2_kernel(const float* __restrict__ W, const float* __restrict__ b,
                             const float* __restrict__ s_prev, const float* __restrict__ ab_prev,
                             float* __restrict__ Wp, float* __restrict__ bp) {
    int g = threadIdx.x; // 256 threads
    float bacc = b[g];
    for (int d = 0; d < HH; ++d) {
        float w = W[d * GG + g];
        bacc += ab_prev[d] * w;
        Wp[d * GG + g] = s_prev[d] * w;
    }
    bp[g] = bacc;
}

// ---------------- init per-call state ----------------
__global__ void init_kernel(float* st_h, float* st_c, float* st_acc, float* st_m, float* st_d) {
    int i = blockIdx.x * blockDim.x + threadIdx.x;
    int n = 3 * BB * HH;
    if (i < n) { st_h[i] = 0.f; st_c[i] = 0.f; st_acc[i] = 0.f; }
    if (i < 3 * BB) { st_m[i] = -3.0e38f; st_d[i] = 0.f; }
}

// ---------------- helpers ----------------
__device__ __forceinline__ f32x4 ld4(const float* p) { return *reinterpret_cast<const f32x4*>(p); }
__device__ __forceinline__ void st4(float* p, f32x4 v) { *reinterpret_cast<f32x4*>(p) = v; }
__device__ __forceinline__ bf16x8 ldbf(const ushort_t* p) { return *reinterpret_cast<const bf16x8*>(p); }
__device__ __forceinline__ int cvtpk(float a, float b) {
    int r; asm("v_cvt_pk_bf16_f32 %0, %1, %2" : "=v"(r) : "v"(a), "v"(b)); return r;
}
__device__ __forceinline__ float sigm(float x) { return __fdividef(1.f, 1.f + __expf(-x)); }
#define MFMA(a, b, c) c = __builtin_amdgcn_mfma_f32_16x16x32_bf16(a, b, c, 0, 0, 0)

// Raw barrier: drain LDS ops (publish visibility) but let vmcnt float across.
// __syncthreads() would emit s_waitcnt vmcnt(0) -- the r13 per-step drain stall.
__device__ __forceinline__ void step_barrier() {
    asm volatile("s_waitcnt lgkmcnt(0)" ::: "memory");
    __builtin_amdgcn_s_barrier();
    __builtin_amdgcn_sched_barrier(0);
}

// ---------------- prep: fp32 weight matrix -> hi/lo bf16 A-fragments, per-lane layout ----
__global__ void prep_frags(const float* __restrict__ M, int KT, ushort_t* __restrict__ outF) {
    int idx = blockIdx.x * 256 + threadIdx.x;
    int tot = 16 * KT * 512;
    if (idx >= tot) return;
    int e = idx & 7, l = (idx >> 3) & 63, f = idx >> 9;
    int kt = f % KT, gw = f / KT;
    int g = gw & 3, w = gw >> 2;
    int r = l & 15, q = l >> 4;
    int k = 32 * kt + 8 * q + e;
    int col = 64 * g + 16 * w + r;
    float v = M[(size_t)k * GG + col];
    int hb = cvtpk(v, v) & 0xffff;
    float hf = __int_as_float(hb << 16);
    float lo = v - hf;
    int lb = cvtpk(lo, lo) & 0xffff;
    outF[(size_t)(f * 2 + 0) * 512 + l * 8 + e] = (ushort_t)hb;
    outF[(size_t)(f * 2 + 1) * 512 + l * 8 + e] = (ushort_t)lb;
}

// ---------------- prep: fp32 array -> hi/lo bf16 planes (elementwise, vectorized) ----
__global__ void prep_planes(const float* __restrict__ in, ushort_t* __restrict__ hi,
                            ushort_t* __restrict__ lo, int n4) {
    int i = blockIdx.x * 256 + threadIdx.x;
    if (i >= n4) return;
    f32x4 v = reinterpret_cast<const f32x4*>(in)[i];
    int p0 = cvtpk(v[0], v[1]), p1 = cvtpk(v[2], v[3]);
    float a0 = v[0] - __int_as_float(p0 << 16);
    float a1 = v[1] - __int_as_float(p0 & 0xffff0000);
    float a2 = v[2] - __int_as_float(p1 << 16);
    float a3 = v[3] - __int_as_float(p1 & 0xffff0000);
    int q0 = cvtpk(a0, a1), q1 = cvtpk(a2, a3);
    reinterpret_cast<int2*>(hi)[i] = make_int2(p0, p1);
    reinterpret_cast<int2*>(lo)[i] = make_int2(q0, q1);
}

// ---------------- MFMA recurrent kernel: raw barriers + ZX software pipeline ----------------
// Block = 16 rows, 4 waves. Wave w owns gate-cols {64g+16w+..}; lane (r,q) holds all 4
// gates of (row r, units 16w+4q..+4) -> in-lane c/h update. h published as bf16 hi/lo
// planes in LDS. ZX pipeline: z_x(t+1)=bias+W.x(t+1) computed during step t (independent
// of h) so step t's h-dependent chain is only 6 MFMAs/gate. x prefetch depth 2; Hout
// stores deferred one step; vmcnt never drained at barriers (step_barrier).
struct RecFArgs {
    const ushort_t* xhi[3]; const ushort_t* xlo[3]; long sB[3]; long sT[3]; int K[3];
    const ushort_t* UF[3]; const ushort_t* WF[3]; const float* bias[3];
    ushort_t* Hhi[3]; ushort_t* Hlo[3];   // nullptr -> skip
    float* st_h[3]; float* st_c[3]; float* st_acc[3];
    float* st_m[3]; float* st_d[3];
    const float* wv[3]; const float* abv[3]; const float* sbn[3];
    float* a_out[3];
    int last[3]; int first[3];
};

template<int KT>   // x K-tiles: 1 (K=32, layer1) or 2 (K=64)
__device__ __forceinline__ void rec_body(const RecFArgs& A, const int seg, const int b0,
                                         ushort_t* hbf, float* scoreP) {
    const int tid = threadIdx.x;
    const int w = tid >> 6;
    const int l = tid & 63;
    const int r = l & 15;
    const int q = l >> 4;
    const int cw = w << 4;
    const int grow = b0 + r;

    const bf16x8* UF = reinterpret_cast<const bf16x8*>(A.UF[seg]);
    const bf16x8* WF = reinterpret_cast<const bf16x8*>(A.WF[seg]);
#define LDU(g,kt,p_) UF[(((((w<<2)+(g))*2+(kt))*2)+(p_))*64 + l]
#define LDW(g,kt,p_) WF[(((((w<<2)+(g))*KT+(kt))*2)+(p_))*64 + l]
    bf16x8 uh00=LDU(0,0,0), uh01=LDU(0,1,0), uh10=LDU(1,0,0), uh11=LDU(1,1,0),
           uh20=LDU(2,0,0), uh21=LDU(2,1,0), uh30=LDU(3,0,0), uh31=LDU(3,1,0);
    bf16x8 ul00=LDU(0,0,1), ul01=LDU(0,1,1), ul10=LDU(1,0,1), ul11=LDU(1,1,1),
           ul20=LDU(2,0,1), ul21=LDU(2,1,1), ul30=LDU(3,0,1), ul31=LDU(3,1,1);
    bf16x8 wh00=LDW(0,0,0), wh10=LDW(1,0,0), wh20=LDW(2,0,0), wh30=LDW(3,0,0);
    bf16x8 wl00=LDW(0,0,1), wl10=LDW(1,0,1), wl20=LDW(2,0,1), wl30=LDW(3,0,1);
    bf16x8 wh01{}, wh11{}, wh21{}, wh31{}, wl01{}, wl11{}, wl21{}, wl31{};
    if constexpr (KT == 2) {
        wh01=LDW(0,1,0); wh11=LDW(1,1,0); wh21=LDW(2,1,0); wh31=LDW(3,1,0);
        wl01=LDW(0,1,1); wl11=LDW(1,1,1); wl21=LDW(2,1,1); wl31=LDW(3,1,1);
    }

    f32x4 bias40 = ld4(A.bias[seg] +   0 + cw + 4 * q);
    f32x4 bias41 = ld4(A.bias[seg] +  64 + cw + 4 * q);
    f32x4 bias42 = ld4(A.bias[seg] + 128 + cw + 4 * q);
    f32x4 bias43 = ld4(A.bias[seg] + 192 + cw + 4 * q);
    f32x4 wv4 = ld4(A.wv[seg] + cw + 4 * q);      // own 4 units only

    f32x4 c4   = ld4(A.st_c[seg]   + (size_t)grow * HH + cw + 4 * q);
    f32x4 h4   = ld4(A.st_h[seg]   + (size_t)grow * HH + cw + 4 * q);
    f32x4 acc4 = ld4(A.st_acc[seg] + (size_t)grow * HH + cw + 4 * q);
    float m_b = A.st_m[seg][grow];
    float d_b = A.st_d[seg][grow];

    int2 hs_hi, hs_lo;     // h planes of previous step (deferred global store)
    auto publish = [&](int slot, f32x4 hv) {
        int p0 = cvtpk(hv[0], hv[1]), p1 = cvtpk(hv[2], hv[3]);
        float a0 = hv[0] - __int_as_float(p0 << 16);
        float a1 = hv[1] - __int_as_float(p0 & 0xffff0000);
        float a2 = hv[2] - __int_as_float(p1 << 16);
        float a3 = hv[3] - __int_as_float(p1 & 0xffff0000);
        int q0 = cvtpk(a0, a1), q1 = cvtpk(a2, a3);
        hs_hi = make_int2(p0, p1); hs_lo = make_int2(q0, q1);
        *reinterpret_cast<int2*>(hbf + ((slot * 2 + 0) * 16 + r) * HSTR + cw + 4 * q) = hs_hi;
        *reinterpret_cast<int2*>(hbf + ((slot * 2 + 1) * 16 + r) * HSTR + cw + 4 * q) = hs_lo;
        float part = hv[0] * wv4[0];
        part = fmaf(hv[1], wv4[1], part);
        part = fmaf(hv[2], wv4[2], part);
        part = fmaf(hv[3], wv4[3], part);
        part += __shfl_xor(part, 16);
        part += __shfl_xor(part, 32);
        if (q == 0) scoreP[(slot * 4 + w) * 16 + r] = part;
    };

    publish(0, h4);   // carried h -> slot 0 (consumed at t=0)

    const ushort_t* xhib = A.xhi[seg] + (size_t)grow * A.sB[seg];
    const ushort_t* xlob = A.xlo[seg] + (size_t)grow * A.sB[seg];
    const long sT = A.sT[seg];

    auto xload = [&](int t, bf16x8& h0, bf16x8& l0, bf16x8& h1, bf16x8& l1) {
        const ushort_t* ph = xhib + (size_t)t * sT + 8 * q;
        const ushort_t* pl = xlob + (size_t)t * sT + 8 * q;
        h0 = ldbf(ph); l0 = ldbf(pl);
        if constexpr (KT == 2) { h1 = ldbf(ph + 32); l1 = ldbf(pl + 32); }
    };

    // ZX(t) = bias + W.x(t), 3-term (same accumulation order as r13's W-phase)
    f32x4 ZX0, ZX1, ZX2, ZX3;
    auto buildZX = [&](bf16x8 xh0, bf16x8 xl0, bf16x8 xh1, bf16x8 xl1) {
        ZX0 = bias40; ZX1 = bias41; ZX2 = bias42; ZX3 = bias43;
        MFMA(wh00, xh0, ZX0); MFMA(wh00, xl0, ZX0); MFMA(wl00, xh0, ZX0);
        if constexpr (KT == 2) { MFMA(wh01, xh1, ZX0); MFMA(wh01, xl1, ZX0); MFMA(wl01, xh1, ZX0); }
        MFMA(wh10, xh0, ZX1); MFMA(wh10, xl0, ZX1); MFMA(wl10, xh0, ZX1);
        if constexpr (KT == 2) { MFMA(wh11, xh1, ZX1); MFMA(wh11, xl1, ZX1); MFMA(wl11, xh1, ZX1); }
        MFMA(wh20, xh0, ZX2); MFMA(wh20, xl0, ZX2); MFMA(wl20, xh0, ZX2);
        if constexpr (KT == 2) { MFMA(wh21, xh1, ZX2); MFMA(wh21, xl1, ZX2); MFMA(wl21, xh1, ZX2); }
        MFMA(wh30, xh0, ZX3); MFMA(wh30, xl0, ZX3); MFMA(wl30, xh0, ZX3);
        if constexpr (KT == 2) { MFMA(wh31, xh1, ZX3); MFMA(wh31, xl1, ZX3); MFMA(wl31, xh1, ZX3); }
    };

    // prologue: ZX(0) from x(0); prefetch x(1) -> xc, x(2) -> xn
    {
        bf16x8 x0h0, x0l0, x0h1{}, x0l1{};
        xload(0, x0h0, x0l0, x0h1, x0l1);
        buildZX(x0h0, x0l0, x0h1, x0l1);
    }
    bf16x8 xc_h0, xc_l0, xc_h1{}, xc_l1{};
    bf16x8 xn_h0, xn_l0, xn_h1{}, xn_l1{};
    xload(1 < TC ? 1 : TC - 1, xc_h0, xc_l0, xc_h1, xc_l1);
    xload(2 < TC ? 2 : TC - 1, xn_h0, xn_l0, xn_h1, xn_l1);
    step_barrier();

    const bool first = A.first[seg] != 0;
    ushort_t* Hhi = A.Hhi[seg];
    ushort_t* Hlo = A.Hlo[seg];

#pragma unroll 2
    for (int t = 0; t < TC; ++t) {
        const int pr = t & 1;
        // deferred Hout store of h_{t-1} (vmcnt floats across barriers now)
        if (Hhi && t > 0) {
            size_t ho = (size_t)grow * (TC * HH) + (size_t)(t - 1) * HH + cw + 4 * q;
            *reinterpret_cast<int2*>(Hhi + ho) = hs_hi;
            *reinterpret_cast<int2*>(Hlo + ho) = hs_lo;
        }
        // attention merge for h_{t-1}
        float sc = scoreP[(pr * 4 + q) * 16 + r];
        sc += __shfl_xor(sc, 16);
        sc += __shfl_xor(sc, 32);
        if (!(first && t == 0)) {
            float mn = fmaxf(m_b, sc);
            float corr = __expf(m_b - mn);
            float p = __expf(sc - mn);
            d_b = d_b * corr + p;
            acc4 = acc4 * corr + p * h4;
            m_b = mn;
        }

        // B-fragments of h_{t-1}: direct bf16 LDS reads
        const ushort_t* hbh = hbf + (pr * 2 + 0) * 16 * HSTR + r * HSTR;
        const ushort_t* hbl = hbf + (pr * 2 + 1) * 16 * HSTR + r * HSTR;
        bf16x8 bh0 = ldbf(hbh + 8 * q);
        bf16x8 bh1 = ldbf(hbh + 32 + 8 * q);
        bf16x8 bl0 = ldbf(hbl + 8 * q);
        bf16x8 bl1 = ldbf(hbl + 32 + 8 * q);

        // C = ZX(t) (precomputed), then U-MFMAs (6/gate, same order as r13)
        f32x4 C0 = ZX0, C1 = ZX1, C2 = ZX2, C3 = ZX3;
        MFMA(uh00, bh0, C0); MFMA(uh00, bl0, C0); MFMA(ul00, bh0, C0);
        MFMA(uh01, bh1, C0); MFMA(uh01, bl1, C0); MFMA(ul01, bh1, C0);
        MFMA(uh10, bh0, C1); MFMA(uh10, bl0, C1); MFMA(ul10, bh0, C1);
        MFMA(uh11, bh1, C1); MFMA(uh11, bl1, C1); MFMA(ul11, bh1, C1);
        MFMA(uh20, bh0, C2); MFMA(uh20, bl0, C2); MFMA(ul20, bh0, C2);
        MFMA(uh21, bh1, C2); MFMA(uh21, bl1, C2); MFMA(ul21, bh1, C2);
        MFMA(uh30, bh0, C3); MFMA(uh30, bl0, C3); MFMA(ul30, bh0, C3);
        MFMA(uh31, bh1, C3); MFMA(uh31, bl1, C3); MFMA(ul31, bh1, C3);

        // ZX(t+1) from xc = x(t+1): independent of h, fills U-chain stalls
        buildZX(xc_h0, xc_l0, xc_h1, xc_l1);
        // rotate prefetch: xc <- xn = x(t+2); issue load x(t+3) -> xn
        xc_h0 = xn_h0; xc_l0 = xn_l0;
        if constexpr (KT == 2) { xc_h1 = xn_h1; xc_l1 = xn_l1; }
        { int tn = (t + 3 < TC) ? t + 3 : TC - 1; xload(tn, xn_h0, xn_l0, xn_h1, xn_l1); }

        // activation + state update
#pragma unroll
        for (int i = 0; i < 4; ++i) {
            float zi = sigm(C0[i]);
            float zf = sigm(C1[i]);
            float zg = fmaxf(C2[i], 0.f);
            float zo = sigm(C3[i]);
            c4[i] = fmaf(zf, c4[i], zi * zg);
            h4[i] = zo * fmaxf(c4[i], 0.f);
        }
        publish(pr ^ 1, h4);
        step_barrier();
    }

    // post-loop: final Hout store of h_{TC-1}
    if (Hhi) {
        size_t ho = (size_t)grow * (TC * HH) + (size_t)(TC - 1) * HH + cw + 4 * q;
        *reinterpret_cast<int2*>(Hhi + ho) = hs_hi;
        *reinterpret_cast<int2*>(Hlo + ho) = hs_lo;
    }
    // last chunk: merge h_{TC-1}'s score (slot 0, TC even) and emit attention output
    if (A.last[seg]) {
        float sc = scoreP[(0 * 4 + q) * 16 + r];
        sc += __shfl_xor(sc, 16);
        sc += __shfl_xor(sc, 32);
        float mn = fmaxf(m_b, sc);
        float corr = __expf(m_b - mn);
        float p = __expf(sc - mn);
        d_b = d_b * corr + p;
        acc4 = acc4 * corr + p * h4;
        m_b = mn;
        f32x4 sb = ld4(A.sbn[seg] + cw + 4 * q);
        f32x4 ab = ld4(A.abv[seg] + cw + 4 * q);
        f32x4 res;
#pragma unroll
        for (int i = 0; i < 4; ++i)
            res[i] = sb[i] * __fdividef(acc4[i], d_b) + ab[i];
        st4(A.a_out[seg] + (size_t)grow * HH + cw + 4 * q, res);
    }
    st4(A.st_c[seg]   + (size_t)grow * HH + cw + 4 * q, c4);
    st4(A.st_h[seg]   + (size_t)grow * HH + cw + 4 * q, h4);
    st4(A.st_acc[seg] + (size_t)grow * HH + cw + 4 * q, acc4);
    if (w == 0 && q == 0) { A.st_m[seg][grow] = m_b; A.st_d[seg][grow] = d_b; }
#undef LDU
#undef LDW
}

__global__ __launch_bounds__(256, 1) void rec_mfma(RecFArgs A) {
    __shared__ ushort_t hbf[2 * 2 * 16 * HSTR];   // 9.2 KB: parity x {hi,lo} x [16][72]
    __shared__ float scoreP[2 * 4 * 16];          // 512 B: parity x wave x row
    const int seg = blockIdx.x >> 6;              // NBLK = 64
    const int b0 = (blockIdx.x & (NBLK - 1)) << 4;
    if (A.K[seg] == 32) rec_body<1>(A, seg, b0, hbf, scoreP);
    else                rec_body<2>(A, seg, b0, hbf, scoreP);
}

// ---------------- final: out[b] = db + sum_{l,j} a[l][b][j]*dw[l*64+j] ----------------
__global__ void final_kernel(const float* __restrict__ a, const float* __restrict__ dw,
                             const float* __restrict__ db, float* __restrict__ out) {
    int b = blockIdx.x * blockDim.x + threadIdx.x;
    if (b >= BB) return;
    float acc = db[0];
    for (int l = 0; l < 3; ++l)
        for (int j = 0; j < HH; ++j)
            acc += a[(l * BB + b) * HH + j] * dw[l * HH + j];
    out[b] = acc;
}

extern "C" void kernel_launch(void* const* d_in, const int* in_sizes, int n_in,
                              void* d_out, int out_size, void* d_ws, size_t ws_size,
                              hipStream_t stream) {
    (void)in_sizes; (void)n_in; (void)out_size; (void)ws_size;
    const float* x = (const float*)d_in[0];
    const float* w[3]    = {(const float*)d_in[1],  (const float*)d_in[10], (const float*)d_in[19]};
    const float* uu[3]   = {(const float*)d_in[2],  (const float*)d_in[11], (const float*)d_in[20]};
    const float* bi[3]   = {(const float*)d_in[3],  (const float*)d_in[12], (const float*)d_in[21]};
    const float* gam[3]  = {(const float*)d_in[4],  (const float*)d_in[13], (const float*)d_in[22]};
    const float* bet[3]  = {(const float*)d_in[5],  (const float*)d_in[14], (const float*)d_in[23]};
    const float* mea[3]  = {(const float*)d_in[6],  (const float*)d_in[15], (const float*)d_in[24]};
    const float* var[3]  = {(const float*)d_in[7],  (const float*)d_in[16], (const float*)d_in[25]};
    const float* atw[3]  = {(const float*)d_in[8],  (const float*)d_in[17], (const float*)d_in[26]};
    const float* atv[3]  = {(const float*)d_in[9],  (const float*)d_in[18], (const float*)d_in[27]};
    const float* dw = (const float*)d_in[28];
    const float* db = (const float*)d_in[29];

    float* ws = (float*)d_ws;
    size_t off = 0;
    // cross-layer h planes (bf16 hi/lo), parity double-buffered
    ushort_t* Hhi[2][2]; ushort_t* Hlo[2][2];
    for (int l = 0; l < 2; ++l)
        for (int p = 0; p < 2; ++p) {
            Hhi[l][p] = (ushort_t*)(ws + off); off += (size_t)BB * TC * HH / 2;
            Hlo[l][p] = (ushort_t*)(ws + off); off += (size_t)BB * TC * HH / 2;
        }
    // layer-1 input planes (bf16 hi/lo)
    ushort_t* Xhi = (ushort_t*)(ws + off); off += (size_t)BB * TT * FF / 2;
    ushort_t* Xlo = (ushort_t*)(ws + off); off += (size_t)BB * TT * FF / 2;
    float* st_h  = ws + off; off += 3 * BB * HH;
    float* st_c  = ws + off; off += 3 * BB * HH;
    float* st_ac = ws + off; off += 3 * BB * HH;
    float* st_m  = ws + off; off += 3 * BB;
    float* st_d  = ws + off; off += 3 * BB;
    float* s_ws  = ws + off; off += 3 * HH;
    float* ab_ws = ws + off; off += 3 * HH;
    float* wv_ws = ws + off; off += 3 * HH;
    float* W2p   = ws + off; off += HH * GG;
    float* W3p   = ws + off; off += HH * GG;
    float* b2p   = ws + off; off += GG;
    float* b3p   = ws + off; off += GG;
    float* a_ws  = ws + off; off += 3 * BB * HH;
    ushort_t* UFb[3]; ushort_t* WFb[3];
    for (int l = 0; l < 3; ++l) { UFb[l] = (ushort_t*)(ws + off); off += 16384; }  // 64KB each
    for (int l = 0; l < 3; ++l) { WFb[l] = (ushort_t*)(ws + off); off += 16384; }

    for (int l = 0; l < 3; ++l)
        fold1_kernel<<<1, 64, 0, stream>>>(gam[l], bet[l], mea[l], var[l], atw[l], atv[l],
                                           s_ws + l * HH, ab_ws + l * HH, wv_ws + l * HH);
    fold2_kernel<<<1, 256, 0, stream>>>(w[1], bi[1], s_ws + 0 * HH, ab_ws + 0 * HH, W2p, b2p);
    fold2_kernel<<<1, 256, 0, stream>>>(w[2], bi[2], s_ws + 1 * HH, ab_ws + 1 * HH, W3p, b3p);
    init_kernel<<<(3 * BB * HH + 255) / 256, 256, 0, stream>>>(st_h, st_c, st_ac, st_m, st_d);

    // pre-build bf16 weight fragments and x planes
    for (int l = 0; l < 3; ++l)
        prep_frags<<<64, 256, 0, stream>>>(uu[l], 2, UFb[l]);
    prep_frags<<<32, 256, 0, stream>>>(w[0], 1, WFb[0]);
    prep_frags<<<64, 256, 0, stream>>>(W2p, 2, WFb[1]);
    prep_frags<<<64, 256, 0, stream>>>(W3p, 2, WFb[2]);
    {
        int n4 = BB * TT * FF / 4;
        prep_planes<<<(n4 + 255) / 256, 256, 0, stream>>>(x, Xhi, Xlo, n4);
    }

    const float* bl[3] = {bi[0], b2p, b3p};

    // software pipeline: at step s, layer l processes chunk s-l
    for (int s = 0; s <= NCHUNK - 1 + 2; ++s) {
        RecFArgs ra;
        int nseg = 0;
        for (int l = 0; l < 3; ++l) {
            int cpos = s - l;
            if (cpos < 0 || cpos >= NCHUNK) continue;
            if (l == 0) {
                ra.xhi[nseg] = Xhi + (size_t)cpos * TC * FF;
                ra.xlo[nseg] = Xlo + (size_t)cpos * TC * FF;
                ra.sB[nseg] = (long)TT * FF;
                ra.sT[nseg] = FF;
                ra.K[nseg] = 32;
            } else {
                int par = (s & 1) ^ 1;               // written by layer l-1 at step s-1
                ra.xhi[nseg] = Hhi[l - 1][par];
                ra.xlo[nseg] = Hlo[l - 1][par];
                ra.sB[nseg] = (long)TC * HH;
                ra.sT[nseg] = HH;
                ra.K[nseg] = 64;
            }
            ra.UF[nseg] = UFb[l]; ra.WF[nseg] = WFb[l]; ra.bias[nseg] = bl[l];
            ra.Hhi[nseg] = (l < 2) ? Hhi[l][s & 1] : (ushort_t*)0;
            ra.Hlo[nseg] = (l < 2) ? Hlo[l][s & 1] : (ushort_t*)0;
            ra.st_h[nseg] = st_h + l * BB * HH;
            ra.st_c[nseg] = st_c + l * BB * HH;
            ra.st_acc[nseg] = st_ac + l * BB * HH;
            ra.st_m[nseg] = st_m + l * BB;
            ra.st_d[nseg] = st_d + l * BB;
            ra.wv[nseg]  = wv_ws + l * HH;
            ra.abv[nseg] = ab_ws + l * HH;
            ra.sbn[nseg] = s_ws + l * HH;
            ra.a_out[nseg] = a_ws + l * BB * HH;
            ra.last[nseg]  = (cpos == NCHUNK - 1) ? 1 : 0;
            ra.first[nseg] = (cpos == 0) ? 1 : 0;
            ++nseg;
        }
        if (!nseg) continue;
        rec_mfma<<<nseg * NBLK, 256, 0, stream>>>(ra);
    }
    final_kernel<<<(BB + 255) / 256, 256, 0, stream>>>(a_ws, dw, db, (float*)d_out);
}